// Round 3
// 156.247 us; speedup vs baseline: 1.0064x; 1.0064x over previous
//
#include <hip/hip_runtime.h>
#include <stdint.h>

typedef __bf16 bf16;
typedef __attribute__((ext_vector_type(8))) __bf16 bf16x8;
typedef __attribute__((ext_vector_type(4))) __bf16 bf16x4;
typedef __attribute__((ext_vector_type(4))) float  f32x4;

#define ATT_SCALE 0.125f   // 1/sqrt(64), folded into Q at GEMM epilogue

// ---------------------------------------------------------------------------
// async 16B global -> LDS (wave-uniform LDS base + lane*16, per-lane gaddr)
// ---------------------------------------------------------------------------
__device__ __forceinline__ void async16(void* lds, const void* g) {
  __builtin_amdgcn_global_load_lds(
      (__attribute__((address_space(1))) void*)(void*)g,
      (__attribute__((address_space(3))) void*)lds,
      16, 0, 0);
}

// ---------------------------------------------------------------------------
// Fused prep: blocks [0,3072) convert x fp32->bf16 (8 elems/thread);
//             blocks [3072,4800) transpose W [768x2304] fp32 -> Wt bf16.
// ---------------------------------------------------------------------------
__global__ void prep_kernel(const float* __restrict__ x, bf16* __restrict__ y,
                            const float* __restrict__ W, bf16* __restrict__ Wt) {
  __shared__ float tile[32][33];
  const int tid = threadIdx.x;
  if (blockIdx.x < 3072) {
    size_t i = ((size_t)blockIdx.x * 256 + tid) * 8;
    float4 a = *(const float4*)(x + i);
    float4 b = *(const float4*)(x + i + 4);
    bf16x8 o;
    o[0] = (bf16)a.x; o[1] = (bf16)a.y; o[2] = (bf16)a.z; o[3] = (bf16)a.w;
    o[4] = (bf16)b.x; o[5] = (bf16)b.y; o[6] = (bf16)b.z; o[7] = (bf16)b.w;
    *(bf16x8*)(y + i) = o;
  } else {
    const int bid = blockIdx.x - 3072;        // 0..1727
    const int tx = tid & 31, ty = tid >> 5;   // 32 x 8
    const int n0 = (bid % 72) * 32, k0 = (bid / 72) * 32;
#pragma unroll
    for (int r = 0; r < 4; ++r)
      tile[ty + r * 8][tx] = W[(size_t)(k0 + ty + r * 8) * 2304 + n0 + tx];
    __syncthreads();
#pragma unroll
    for (int r = 0; r < 4; ++r)
      Wt[(size_t)(n0 + ty + r * 8) * 768 + k0 + tx] = (bf16)tile[tx][ty + r * 8];
  }
}

// ---------------------------------------------------------------------------
// QKV GEMM v2c: 256x256 tile, BK=64, 8 waves (2M x 4N), 8-phase schedule.
//   v2/v2b failed with BIT-IDENTICAL wrong output across both builds ->
//   deterministic bug in code identical in both: the PROLOGUE. Its six
//   stageH calls are independent VMEM intrinsics; the machine scheduler
//   clusters them by base pointer (A-stream vs B-stream), permuting issue
//   order -> counted vmcnt(4)'s "oldest 8 = tile 0" property breaks ->
//   ph3 reads tile0.A1 while its DMA is in flight. Fix:
//     (1) sched_barrier(0) between every prologue stage (pin issue order)
//     (2) prologue drains vmcnt(0) (order-independent; one-time cost)
//     (3) sched_barrier(0) after each in-loop stage (defense in depth;
//         phase boundaries were already fenced in v2b)
//   Steady state re-derived with prologue drain: at P0-ph4 outstanding =
//   {t1.B1,t1.A1,t2.B0,t2.A0}; vmcnt(4) completes t1 exactly (t1.B0/A0
//   drained at prologue). All later boundaries unchanged:
//     reads/tile: ph1 (A0,B0) ph2 (B1) ph3 (A1) ph4 (regs only)
//     stages/pair: ph1 t+1.B1  ph2 t+1.A1  ph3 t+2.B0  ph4 t+2.A0
//                  ph5 t+2.B1  ph6 t+2.A1  ph7 t+3.B0  ph8 t+3.A0
//   vmcnt(4) at ph4/ph8 only (in-order counter completes exactly the next
//   tile's remaining loads, keeps 4 in flight).
// ---------------------------------------------------------------------------
__global__ __launch_bounds__(512, 2)
void qkv_gemm_kernel(const bf16* __restrict__ A, const bf16* __restrict__ Bw,
                     const float* __restrict__ bias,
                     bf16* __restrict__ Qo, bf16* __restrict__ Ko,
                     bf16* __restrict__ Vo) {
  __shared__ __align__(16) char lds[131072];

  const int tid  = threadIdx.x;
  const int wave = tid >> 6, lane = tid & 63;
  const int quad = lane >> 4, mn = lane & 15;
  const int wr = wave >> 2, wc = wave & 3;      // 2 x 4 wave grid
  const int m0 = blockIdx.y * 256;
  const int n0 = blockIdx.x * 256;

  f32x4 acc[8][4] = {};

  const int lrow = lane >> 3;           // 0..7 (row within 8-row group)
  const int cg   = (lane & 7) ^ lrow;   // pre-swizzled global 16B chunk

  // stage one half-tile (128 rows x 64 cols): op 0=A 1=B, half 0/1, tile t
  auto stageH = [&](int t, int op, int half) {
    char* dst = lds + (t & 1) * 65536 + op * 32768 + half * 16384;
    const bf16* src = op ? Bw : A;
    const int  r0   = (op ? n0 : m0) + half * 128;
#pragma unroll
    for (int u = 0; u < 2; ++u) {
      const int grp = wave * 2 + u;          // 0..15 (8-row group)
      const int row = grp * 8 + lrow;        // 0..127
      async16(dst + grp * 1024 + lane * 16,
              src + (size_t)(r0 + row) * 768 + t * 64 + cg * 8);
    }
  };

  bf16x8 af[4][2], bf0[2][2], bf1[2][2];
  auto ldA = [&](int t, int a) {
    const char* base = lds + (t & 1) * 65536 + wr * 16384;
#pragma unroll
    for (int i = 0; i < 4; ++i) {
      const int r = a * 64 + i * 16 + mn;    // row within staging half
#pragma unroll
      for (int s = 0; s < 2; ++s)
        af[i][s] = *(const bf16x8*)(base + r * 128 + (((s * 4 + quad) ^ (mn & 7)) * 16));
    }
  };
  auto ldB = [&](int t, int b, bf16x8 (&bfr)[2][2]) {
    const char* base = lds + (t & 1) * 65536 + 32768 + (wc >> 1) * 16384;
#pragma unroll
    for (int j = 0; j < 2; ++j) {
      const int r = (wc & 1) * 64 + b * 32 + j * 16 + mn;
#pragma unroll
      for (int s = 0; s < 2; ++s)
        bfr[j][s] = *(const bf16x8*)(base + r * 128 + (((s * 4 + quad) ^ (mn & 7)) * 16));
    }
  };
  auto mm = [&](bf16x8 (&bfr)[2][2], int a, int b) {
    __builtin_amdgcn_s_setprio(1);
#pragma unroll
    for (int i = 0; i < 4; ++i)
#pragma unroll
      for (int j = 0; j < 2; ++j)
#pragma unroll
        for (int s = 0; s < 2; ++s)
          acc[a * 4 + i][b * 2 + j] = __builtin_amdgcn_mfma_f32_16x16x32_bf16(
              af[i][s], bfr[j][s], acc[a * 4 + i][b * 2 + j], 0, 0, 0);
    __builtin_amdgcn_s_setprio(0);
  };

#define SCHED0() __builtin_amdgcn_sched_barrier(0)
#define BAR()    do { __builtin_amdgcn_s_barrier(); SCHED0(); } while (0)
#define LGKM0()  do { asm volatile("s_waitcnt lgkmcnt(0)" ::: "memory"); SCHED0(); } while (0)
#define VM4()    do { asm volatile("s_waitcnt vmcnt(4)" ::: "memory"); SCHED0(); } while (0)
#define VM0()    do { asm volatile("s_waitcnt vmcnt(0)" ::: "memory"); SCHED0(); } while (0)

  // prologue: t0 complete + t1.B0 + t1.A0 (12 loads), issue-order pinned,
  // then FULL drain (order-independent correctness; one-time cost).
  stageH(0, 1, 0); SCHED0();
  stageH(0, 0, 0); SCHED0();
  stageH(0, 1, 1); SCHED0();
  stageH(0, 0, 1); SCHED0();
  stageH(1, 1, 0); SCHED0();
  stageH(1, 0, 0); SCHED0();
  VM0();
  BAR();

  for (int P = 0; P < 6; ++P) {
    const int t0 = 2 * P, t1 = 2 * P + 1;
    const bool s2 = (t0 + 2) < 12, s3 = (t0 + 3) < 12;

    // ---- tile t0 (buffer 0) ----
    // ph1: quadrant (A0,B0)
    ldA(t0, 0); ldB(t0, 0, bf0);
    stageH(t1, 1, 1); SCHED0();            // t1.B1
    BAR(); LGKM0(); mm(bf0, 0, 0); BAR();
    // ph2: (A0,B1)
    ldB(t0, 1, bf1);
    stageH(t1, 0, 1); SCHED0();            // t1.A1
    BAR(); LGKM0(); mm(bf1, 0, 1); BAR();
    // ph3: (A1,B1)
    ldA(t0, 1);
    if (s2) { stageH(t0 + 2, 1, 0); SCHED0(); }   // t2.B0
    BAR(); LGKM0(); mm(bf1, 1, 1); BAR();
    // ph4: (A1,B0) — register-only reads; counted vmcnt completes tile t1
    if (s2) { stageH(t0 + 2, 0, 0); SCHED0(); }   // t2.A0
    if (P == 5) { VM0(); } else { VM4(); }
    BAR(); mm(bf0, 1, 0); BAR();

    // ---- tile t1 (buffer 1) ----
    // ph5: (A0,B0)
    ldA(t1, 0); ldB(t1, 0, bf0);
    if (s2) { stageH(t0 + 2, 1, 1); SCHED0(); }   // t2.B1
    BAR(); LGKM0(); mm(bf0, 0, 0); BAR();
    // ph6: (A0,B1)
    ldB(t1, 1, bf1);
    if (s2) { stageH(t0 + 2, 0, 1); SCHED0(); }   // t2.A1
    BAR(); LGKM0(); mm(bf1, 0, 1); BAR();
    // ph7: (A1,B1)
    ldA(t1, 1);
    if (s3) { stageH(t0 + 3, 1, 0); SCHED0(); }   // t3.B0
    BAR(); LGKM0(); mm(bf1, 1, 1); BAR();
    // ph8: (A1,B0) — counted vmcnt completes tile t2 for next pair's ph1
    if (s3) { stageH(t0 + 3, 0, 0); SCHED0(); }   // t3.A0
    VM4();
    BAR(); mm(bf0, 1, 0); BAR();
  }

#undef BAR
#undef LGKM0
#undef VM4
#undef VM0
#undef SCHED0

  // epilogue: row = m0 + wr*128 + ai*16 + quad*4 + r ; col = n0 + wc*64 + bj*16 + mn
  const int ng    = n0 + wc * 64;
  const int third = ng / 768;           // 0=Q 1=K 2=V (64-col wave range never spans)
  const int nmod  = ng % 768;
  const float sc  = (third == 0) ? ATT_SCALE : 1.0f;
#pragma unroll
  for (int bj = 0; bj < 4; ++bj) {
    int n = nmod + bj * 16 + mn;
    int h = n >> 6, d = n & 63;
    float bv = bias[third * 768 + n];
#pragma unroll
    for (int ai = 0; ai < 8; ++ai) {
      int m  = m0 + wr * 128 + ai * 16 + quad * 4;
      int b  = m >> 10, t0r = m & 1023;
      size_t bh = (size_t)b * 12 + h;
      if (third == 2) {
        bf16x4 pk;
#pragma unroll
        for (int r = 0; r < 4; ++r) pk[r] = (bf16)(acc[ai][bj][r] + bv);
        *(bf16x4*)(Vo + (bh * 64 + d) * 1024 + t0r) = pk;   // V^T
      } else {
        bf16* dst = (third == 0 ? Qo : Ko) + (bh * 1024 + t0r) * 64 + d;
#pragma unroll
        for (int r = 0; r < 4; ++r) dst[(size_t)r * 64] = (bf16)((acc[ai][bj][r] + bv) * sc);
      }
    }
  }
}

// ---------------------------------------------------------------------------
// Attention v5 = v3 (best measured) + conflict-free S buffer + phase split.
//   Block (bh, y): Q-tiles qta = y and qtb = 15-qta share one KV stream
//   j = 0..qtb. KV tiles DMA'd (XOR swizzle) into double-buffered LDS; one
//   barrier per iter. QK as mfma(kf,qf)=S^T -> b64 S-writes.
//   S buffer: pitch 128B, 8B-chunk XOR swizzle (stored c8 = c8 ^ ((mn&7)<<1),
//   preserving 16B read-pair contiguity) -> S writes & reads <=2-way (free).
//   Phase split per iter: QK(A), QK(B), then SV(A), SV(B) -- B's QK MFMAs
//   cover A's S round-trip latency. S rows wave-private (no barrier).
// ---------------------------------------------------------------------------
__global__ __launch_bounds__(256, 3)
void attn_kernel(const bf16* __restrict__ Q, const bf16* __restrict__ K,
                 const bf16* __restrict__ Vt, float* __restrict__ out) {
  __shared__ __align__(16) char lds[49152];
  // buf p at lds + p*16384: K 64x128B, then V 64x128B (both XOR-swizzled)
  char* ldsS = lds + 32768;              // 128 rows x 128B (A-half, B-half)

  const int tid  = threadIdx.x;
  const int wave = tid >> 6, lane = tid & 63;
  const int quad = lane >> 4, mn = lane & 15;
  const int bh  = blockIdx.x;
  const int qta = blockIdx.y;            // 0..7
  const int qtb = 15 - qta;              // 8..15
  const int qa0 = qta * 64, qb0 = qtb * 64;

  const bf16* Qg  = Q  + (size_t)bh * 65536;
  const bf16* Kg0 = K  + (size_t)bh * 65536;
  const bf16* Vg0 = Vt + (size_t)bh * 65536;

  // Q fragments: lane mn -> row base+mn, d = quad*8.. / 32+quad*8..
  bf16x8 qfA[2], qfB[2];
  {
    const bf16* ra = Qg + (size_t)(qa0 + wave * 16 + mn) * 64;
    qfA[0] = *(const bf16x8*)(ra + quad * 8);
    qfA[1] = *(const bf16x8*)(ra + 32 + quad * 8);
    const bf16* rb = Qg + (size_t)(qb0 + wave * 16 + mn) * 64;
    qfB[0] = *(const bf16x8*)(rb + quad * 8);
    qfB[1] = *(const bf16x8*)(rb + 32 + quad * 8);
  }

  f32x4 yA[4] = {}, yB[4] = {};

  const int lrow = lane >> 3;            // 0..7
  const int cg   = (lane & 7) ^ lrow;    // swizzled global chunk

  auto stageKV = [&](int j, char* buf) {
#pragma unroll
    for (int u2 = 0; u2 < 2; ++u2) {
      const int u   = wave * 2 + u2;     // 8-row group 0..7
      const int row = u * 8 + lrow;      // 0..63
      async16(buf + u * 1024 + lane * 16,
              Kg0 + (size_t)(j * 64 + row) * 64 + cg * 8);
      async16(buf + 8192 + u * 1024 + lane * 16,
              Vg0 + (size_t)row * 1024 + j * 64 + cg * 8);
    }
  };

  const int srow = (wave * 16 + mn) * 128;   // within a half (half adds 8192)

  stageKV(0, lds);
  for (int j = 0; j <= qtb; ++j) {
    __syncthreads();                     // drains DMA for buf j&1; WAR for j-2
    if (j < qtb) stageKV(j + 1, lds + ((j + 1) & 1) * 16384);
    char* bK = lds + (j & 1) * 16384;
    char* bV = bK + 8192;

    // hoisted K/V fragments (shared by both halves)
    bf16x8 kf[4][2], vf[4][2];
    const int sw = mn & 7;
#pragma unroll
    for (int ct = 0; ct < 4; ++ct) {
      const int ro = (ct * 16 + mn) * 128;
      kf[ct][0] = *(const bf16x8*)(bK + ro + ((quad)     ^ sw) * 16);
      kf[ct][1] = *(const bf16x8*)(bK + ro + ((4 + quad) ^ sw) * 16);
      vf[ct][0] = *(const bf16x8*)(bV + ro + ((quad)     ^ sw) * 16);
      vf[ct][1] = *(const bf16x8*)(bV + ro + ((4 + quad) ^ sw) * 16);
    }

    auto qk_half = [&](const bf16x8* qf, int half, int qrow, bool diag) {
      // S^T = K Q^T: lane holds (kk = j*64+ct*16+quad*4+r, q = qrow=base+mn)
#pragma unroll
      for (int ct = 0; ct < 4; ++ct) {
        f32x4 a = {};
        a = __builtin_amdgcn_mfma_f32_16x16x32_bf16(kf[ct][0], qf[0], a, 0, 0, 0);
        a = __builtin_amdgcn_mfma_f32_16x16x32_bf16(kf[ct][1], qf[1], a, 0, 0, 0);
        const int kkg = j * 64 + ct * 16 + quad * 4;
        bf16x4 pk;
#pragma unroll
        for (int r = 0; r < 4; ++r) {
          float v = a[r];
          v = v > 0.f ? v : 0.f;
          if (diag && kkg + r > qrow) v = 0.f;
          pk[r] = (bf16)v;
        }
        *(bf16x4*)(ldsS + half * 8192 + srow +
                   (((ct * 4 + quad) ^ (sw << 1)) & 15) * 8) = pk;
      }
    };
    auto sv_half = [&](f32x4* y, int half) {
#pragma unroll
      for (int kb = 0; kb < 2; ++kb) {
        bf16x8 sf = *(const bf16x8*)(ldsS + half * 8192 + srow +
                                     ((kb * 4 + quad) ^ sw) * 16);
#pragma unroll
        for (int ct = 0; ct < 4; ++ct)
          y[ct] = __builtin_amdgcn_mfma_f32_16x16x32_bf16(sf, vf[ct][kb], y[ct], 0, 0, 0);
      }
    };

    if (j <= qta) qk_half(qfA, 0, qa0 + wave * 16 + mn, j == qta);
    qk_half(qfB, 1, qb0 + wave * 16 + mn, j == qtb);
    if (j <= qta) sv_half(yA, 0);
    sv_half(yB, 1);
  }

  // write out: out[b][t][h*64+d]; yacc: q = wave*16+quad*4+r, d = ct*16+mn
  const int b = bh / 12, h = bh % 12;
  {
    float* ob = out + ((size_t)b * 1024 + qa0 + wave * 16 + quad * 4) * 768 + h * 64;
#pragma unroll
    for (int ct = 0; ct < 4; ++ct)
#pragma unroll
      for (int r = 0; r < 4; ++r)
        ob[(size_t)r * 768 + ct * 16 + mn] = yA[ct][r];
  }
  {
    float* ob = out + ((size_t)b * 1024 + qb0 + wave * 16 + quad * 4) * 768 + h * 64;
#pragma unroll
    for (int ct = 0; ct < 4; ++ct)
#pragma unroll
      for (int r = 0; r < 4; ++r)
        ob[(size_t)r * 768 + ct * 16 + mn] = yB[ct][r];
  }
}

// ---------------------------------------------------------------------------
extern "C" void kernel_launch(void* const* d_in, const int* in_sizes, int n_in,
                              void* d_out, int out_size, void* d_ws, size_t ws_size,
                              hipStream_t stream) {
  const float* x    = (const float*)d_in[0];   // [8,1024,768]
  const float* W    = (const float*)d_in[1];   // [768,2304]
  const float* bias = (const float*)d_in[2];   // [2304]
  float* out = (float*)d_out;                  // [8,1024,768]

  char* ws = (char*)d_ws;
  bf16* xb = (bf16*)(ws);                      // 8192*768
  bf16* Wt = (bf16*)(ws + 12582912);           // 2304*768
  bf16* Qb = (bf16*)(ws + 16121856);           // 96*1024*64
  bf16* Kb = (bf16*)(ws + 28704768);           // 96*1024*64
  bf16* Vb = (bf16*)(ws + 41287680);           // 96*64*1024 (V^T)

  prep_kernel<<<4800, 256, 0, stream>>>(x, xb, W, Wt);
  qkv_gemm_kernel<<<dim3(9, 32), 512, 0, stream>>>(xb, Wt, bias, Qb, Kb, Vb);
  attn_kernel<<<dim3(96, 8), 256, 0, stream>>>(Qb, Kb, Vb, out);
}

// Round 4
// 151.448 us; speedup vs baseline: 1.0383x; 1.0317x over previous
//
#include <hip/hip_runtime.h>
#include <stdint.h>

typedef __bf16 bf16;
typedef __attribute__((ext_vector_type(8))) __bf16 bf16x8;
typedef __attribute__((ext_vector_type(4))) __bf16 bf16x4;
typedef __attribute__((ext_vector_type(4))) float  f32x4;

#define ATT_SCALE 0.125f   // 1/sqrt(64), folded into Q at GEMM epilogue

// ---------------------------------------------------------------------------
// async 16B global -> LDS (wave-uniform LDS base + lane*16, per-lane gaddr)
// ---------------------------------------------------------------------------
__device__ __forceinline__ void async16(void* lds, const void* g) {
  __builtin_amdgcn_global_load_lds(
      (__attribute__((address_space(1))) void*)(void*)g,
      (__attribute__((address_space(3))) void*)lds,
      16, 0, 0);
}

// ---------------------------------------------------------------------------
// Fused prep: blocks [0,3072) convert x fp32->bf16 (8 elems/thread);
//             blocks [3072,4800) transpose W [768x2304] fp32 -> Wt bf16.
// ---------------------------------------------------------------------------
__global__ void prep_kernel(const float* __restrict__ x, bf16* __restrict__ y,
                            const float* __restrict__ W, bf16* __restrict__ Wt) {
  __shared__ float tile[32][33];
  const int tid = threadIdx.x;
  if (blockIdx.x < 3072) {
    size_t i = ((size_t)blockIdx.x * 256 + tid) * 8;
    float4 a = *(const float4*)(x + i);
    float4 b = *(const float4*)(x + i + 4);
    bf16x8 o;
    o[0] = (bf16)a.x; o[1] = (bf16)a.y; o[2] = (bf16)a.z; o[3] = (bf16)a.w;
    o[4] = (bf16)b.x; o[5] = (bf16)b.y; o[6] = (bf16)b.z; o[7] = (bf16)b.w;
    *(bf16x8*)(y + i) = o;
  } else {
    const int bid = blockIdx.x - 3072;        // 0..1727
    const int tx = tid & 31, ty = tid >> 5;   // 32 x 8
    const int n0 = (bid % 72) * 32, k0 = (bid / 72) * 32;
#pragma unroll
    for (int r = 0; r < 4; ++r)
      tile[ty + r * 8][tx] = W[(size_t)(k0 + ty + r * 8) * 2304 + n0 + tx];
    __syncthreads();
#pragma unroll
    for (int r = 0; r < 4; ++r)
      Wt[(size_t)(n0 + ty + r * 8) * 768 + k0 + tx] = (bf16)tile[tx][ty + r * 8];
  }
}

// ---------------------------------------------------------------------------
// QKV GEMM (round-0 proven version): C[8192 x 2304] = A[8192 x 768]*Wt^T + b
//   Tile 128x128, BK=64, double-buffered LDS (2x32KB), one barrier per iter.
//   Line-coalesced DMA staging with XOR swizzle -> frag ds_read_b128s
//   conflict-free. 1152 blocks at 2 blocks/CU: good load balance.
//   (8-phase 256x256 experiment measured SLOWER at this shape: 288 blocks
//   x 1 block/CU = 56% slot efficiency + K=768 too short to amortize the
//   deep pipeline. Reverted.)
// ---------------------------------------------------------------------------
__global__ void qkv_gemm_kernel(const bf16* __restrict__ A, const bf16* __restrict__ Bw,
                                const float* __restrict__ bias,
                                bf16* __restrict__ Qo, bf16* __restrict__ Ko,
                                bf16* __restrict__ Vo) {
  __shared__ __align__(16) char lds[65536];   // 2 x (A 16KB + B 16KB)

  const int tid  = threadIdx.x;
  const int wave = tid >> 6, lane = tid & 63;
  const int quad = lane >> 4, mn = lane & 15;
  const int wr = wave >> 1, wc = wave & 1;
  const int m0 = blockIdx.y * 128;
  const int n0 = blockIdx.x * 128;

  f32x4 acc[4][4] = {};

  const int lrow = lane >> 3;           // 0..7  (row within 8-row group)
  const int cg   = (lane & 7) ^ lrow;   // global 16B-chunk index (swizzled)

  auto stage = [&](int kt, char* buf) {
    char* Al = buf;
    char* Bl = buf + 16384;
#pragma unroll
    for (int u = 0; u < 4; ++u) {
      const int t   = wave * 4 + u;      // 8-row group 0..15
      const int row = t * 8 + lrow;      // tile row 0..127
      async16(Al + t * 1024 + lane * 16,
              A  + (size_t)(m0 + row) * 768 + kt + cg * 8);
      async16(Bl + t * 1024 + lane * 16,
              Bw + (size_t)(n0 + row) * 768 + kt + cg * 8);
    }
  };

  stage(0, lds);
  int p = 0;
  for (int kt = 0; kt < 768; kt += 64) {
    __syncthreads();                     // drains DMA into buf p
    if (kt + 64 < 768) stage(kt + 64, lds + (p ^ 1) * 32768);  // prefetch
    char* Al = lds + p * 32768;
    char* Bl = Al + 16384;

#pragma unroll
    for (int s = 0; s < 2; ++s) {        // two K=32 steps within BK=64
      bf16x8 af[4], bfr[4];
      const int csw = ((s * 4 + quad) ^ (mn & 7)) * 16;  // swizzled chunk offset
#pragma unroll
      for (int i = 0; i < 4; ++i) {
        af[i]  = *(const bf16x8*)(Al + (wr * 64 + i * 16 + mn) * 128 + csw);
        bfr[i] = *(const bf16x8*)(Bl + (wc * 64 + i * 16 + mn) * 128 + csw);
      }
#pragma unroll
      for (int i = 0; i < 4; ++i)
#pragma unroll
        for (int j = 0; j < 4; ++j)
          acc[i][j] = __builtin_amdgcn_mfma_f32_16x16x32_bf16(af[i], bfr[j], acc[i][j], 0, 0, 0);
    }
    p ^= 1;
  }

  // epilogue
  const int ng    = n0 + wc * 64;
  const int third = ng / 768;           // 0=Q 1=K 2=V
  const int nmod  = ng % 768;
  const float sc  = (third == 0) ? ATT_SCALE : 1.0f;
#pragma unroll
  for (int ct = 0; ct < 4; ++ct) {
    int n = nmod + ct * 16 + mn;
    int h = n >> 6, d = n & 63;
    float bv = bias[third * 768 + n];
#pragma unroll
    for (int rt = 0; rt < 4; ++rt) {
      int m  = m0 + wr * 64 + rt * 16 + quad * 4;
      int b  = m >> 10, t0 = m & 1023;
      size_t bh = (size_t)b * 12 + h;
      if (third == 2) {
        bf16x4 pk;
#pragma unroll
        for (int r = 0; r < 4; ++r) pk[r] = (bf16)(acc[rt][ct][r] + bv);
        *(bf16x4*)(Vo + (bh * 64 + d) * 1024 + t0) = pk;   // V^T
      } else {
        bf16* dst = (third == 0 ? Qo : Ko) + (bh * 1024 + t0) * 64 + d;
#pragma unroll
        for (int r = 0; r < 4; ++r) dst[(size_t)r * 64] = (bf16)((acc[rt][ct][r] + bv) * sc);
      }
    }
  }
}

// ---------------------------------------------------------------------------
// Attention v6 = v5 + distance-2 KV prefetch with counted vmcnt.
//   v5's per-iter __syncthreads drained a DMA issued only ~16 MFMAs earlier
//   (~80 cyc cover vs 200-900 cyc latency) -> structural stall every iter.
//   v6: triple-buffered KV (3 x 16KB) + S (16KB) = 64KB -> 2 blocks/CU.
//   Iter j: vmcnt(4) completes stage j, leaves stage j+1 in flight
//   (vmcnt(0) only at the last iter, pipeline provably starved); raw
//   s_barrier publishes all waves' stage-j rows; then issue stage j+2
//   (buffer (j+2)%3 == (j-1)%3, WAR-safe: all waves crossed the barrier
//   after finishing iter j-1 reads). Issue order pinned with
//   sched_barrier(0): Qfrags < stage0 < stage1 < (loop stages), so the
//   counted wait's "oldest first" arithmetic holds (round-3 lesson: the
//   scheduler otherwise clusters VMEM by base pointer). S rows stay
//   wave-private: no barrier between QK and SV.
// ---------------------------------------------------------------------------
__global__ __launch_bounds__(256, 2)
void attn_kernel(const bf16* __restrict__ Q, const bf16* __restrict__ K,
                 const bf16* __restrict__ Vt, float* __restrict__ out) {
  __shared__ __align__(16) char lds[65536];
  // buf c at lds + c*16384 (c = j%3): K 64x128B then V 64x128B (XOR-swizzled)
  char* ldsS = lds + 49152;              // 128 rows x 128B (A-half, B-half)

  const int tid  = threadIdx.x;
  const int wave = tid >> 6, lane = tid & 63;
  const int quad = lane >> 4, mn = lane & 15;
  const int bh  = blockIdx.x;
  const int qta = blockIdx.y;            // 0..7
  const int qtb = 15 - qta;              // 8..15
  const int qa0 = qta * 64, qb0 = qtb * 64;

  const bf16* Qg  = Q  + (size_t)bh * 65536;
  const bf16* Kg0 = K  + (size_t)bh * 65536;
  const bf16* Vg0 = Vt + (size_t)bh * 65536;

#define SCHED0() __builtin_amdgcn_sched_barrier(0)

  // Q fragments: lane mn -> row base+mn, d = quad*8.. / 32+quad*8..
  bf16x8 qfA[2], qfB[2];
  {
    const bf16* ra = Qg + (size_t)(qa0 + wave * 16 + mn) * 64;
    qfA[0] = *(const bf16x8*)(ra + quad * 8);
    qfA[1] = *(const bf16x8*)(ra + 32 + quad * 8);
    const bf16* rb = Qg + (size_t)(qb0 + wave * 16 + mn) * 64;
    qfB[0] = *(const bf16x8*)(rb + quad * 8);
    qfB[1] = *(const bf16x8*)(rb + 32 + quad * 8);
  }
  SCHED0();   // pin Q-loads before the staged DMA (vmcnt order discipline)

  f32x4 yA[4] = {}, yB[4] = {};

  const int lrow = lane >> 3;            // 0..7
  const int cg   = (lane & 7) ^ lrow;    // swizzled global chunk

  auto stageKV = [&](int j, char* buf) {
#pragma unroll
    for (int u2 = 0; u2 < 2; ++u2) {
      const int u   = wave * 2 + u2;     // 8-row group 0..7
      const int row = u * 8 + lrow;      // 0..63
      async16(buf + u * 1024 + lane * 16,
              Kg0 + (size_t)(j * 64 + row) * 64 + cg * 8);
      async16(buf + 8192 + u * 1024 + lane * 16,
              Vg0 + (size_t)row * 1024 + j * 64 + cg * 8);
    }
  };

  const int srow = (wave * 16 + mn) * 128;   // within a half (half adds 8192)

  // prologue: distance-2 pipeline (qtb >= 8 always, both stages valid)
  stageKV(0, lds);            SCHED0();
  stageKV(1, lds + 16384);    SCHED0();

  for (int j = 0; j <= qtb; ++j) {
    // complete stage j; keep stage j+1 in flight (4 loads/wave/stage)
    if (j < qtb) { asm volatile("s_waitcnt vmcnt(4)" ::: "memory"); }
    else         { asm volatile("s_waitcnt vmcnt(0)" ::: "memory"); }
    SCHED0();
    __builtin_amdgcn_s_barrier();        // publish all waves' stage-j rows
    SCHED0();
    if (j + 2 <= qtb) { stageKV(j + 2, lds + ((j + 2) % 3) * 16384); SCHED0(); }

    char* bK = lds + (j % 3) * 16384;
    char* bV = bK + 8192;

    // hoisted K/V fragments (shared by both halves)
    bf16x8 kf[4][2], vf[4][2];
    const int sw = mn & 7;
#pragma unroll
    for (int ct = 0; ct < 4; ++ct) {
      const int ro = (ct * 16 + mn) * 128;
      kf[ct][0] = *(const bf16x8*)(bK + ro + ((quad)     ^ sw) * 16);
      kf[ct][1] = *(const bf16x8*)(bK + ro + ((4 + quad) ^ sw) * 16);
      vf[ct][0] = *(const bf16x8*)(bV + ro + ((quad)     ^ sw) * 16);
      vf[ct][1] = *(const bf16x8*)(bV + ro + ((4 + quad) ^ sw) * 16);
    }

    auto qk_half = [&](const bf16x8* qf, int half, int qrow, bool diag) {
      // S^T = K Q^T: lane holds (kk = j*64+ct*16+quad*4+r, q = qrow=base+mn)
#pragma unroll
      for (int ct = 0; ct < 4; ++ct) {
        f32x4 a = {};
        a = __builtin_amdgcn_mfma_f32_16x16x32_bf16(kf[ct][0], qf[0], a, 0, 0, 0);
        a = __builtin_amdgcn_mfma_f32_16x16x32_bf16(kf[ct][1], qf[1], a, 0, 0, 0);
        const int kkg = j * 64 + ct * 16 + quad * 4;
        bf16x4 pk;
#pragma unroll
        for (int r = 0; r < 4; ++r) {
          float v = a[r];
          v = v > 0.f ? v : 0.f;
          if (diag && kkg + r > qrow) v = 0.f;
          pk[r] = (bf16)v;
        }
        *(bf16x4*)(ldsS + half * 8192 + srow +
                   (((ct * 4 + quad) ^ (sw << 1)) & 15) * 8) = pk;
      }
    };
    auto sv_half = [&](f32x4* y, int half) {
#pragma unroll
      for (int kb = 0; kb < 2; ++kb) {
        bf16x8 sf = *(const bf16x8*)(ldsS + half * 8192 + srow +
                                     ((kb * 4 + quad) ^ sw) * 16);
#pragma unroll
        for (int ct = 0; ct < 4; ++ct)
          y[ct] = __builtin_amdgcn_mfma_f32_16x16x32_bf16(sf, vf[ct][kb], y[ct], 0, 0, 0);
      }
    };

    if (j <= qta) qk_half(qfA, 0, qa0 + wave * 16 + mn, j == qta);
    qk_half(qfB, 1, qb0 + wave * 16 + mn, j == qtb);
    if (j <= qta) sv_half(yA, 0);
    sv_half(yB, 1);
  }

#undef SCHED0

  // write out: out[b][t][h*64+d]; yacc: q = wave*16+quad*4+r, d = ct*16+mn
  const int b = bh / 12, h = bh % 12;
  {
    float* ob = out + ((size_t)b * 1024 + qa0 + wave * 16 + quad * 4) * 768 + h * 64;
#pragma unroll
    for (int ct = 0; ct < 4; ++ct)
#pragma unroll
      for (int r = 0; r < 4; ++r)
        ob[(size_t)r * 768 + ct * 16 + mn] = yA[ct][r];
  }
  {
    float* ob = out + ((size_t)b * 1024 + qb0 + wave * 16 + quad * 4) * 768 + h * 64;
#pragma unroll
    for (int ct = 0; ct < 4; ++ct)
#pragma unroll
      for (int r = 0; r < 4; ++r)
        ob[(size_t)r * 768 + ct * 16 + mn] = yB[ct][r];
  }
}

// ---------------------------------------------------------------------------
extern "C" void kernel_launch(void* const* d_in, const int* in_sizes, int n_in,
                              void* d_out, int out_size, void* d_ws, size_t ws_size,
                              hipStream_t stream) {
  const float* x    = (const float*)d_in[0];   // [8,1024,768]
  const float* W    = (const float*)d_in[1];   // [768,2304]
  const float* bias = (const float*)d_in[2];   // [2304]
  float* out = (float*)d_out;                  // [8,1024,768]

  char* ws = (char*)d_ws;
  bf16* xb = (bf16*)(ws);                      // 8192*768
  bf16* Wt = (bf16*)(ws + 12582912);           // 2304*768
  bf16* Qb = (bf16*)(ws + 16121856);           // 96*1024*64
  bf16* Kb = (bf16*)(ws + 28704768);           // 96*1024*64
  bf16* Vb = (bf16*)(ws + 41287680);           // 96*64*1024 (V^T)

  prep_kernel<<<4800, 256, 0, stream>>>(x, xb, W, Wt);
  qkv_gemm_kernel<<<dim3(18, 64), 256, 0, stream>>>(xb, Wt, bias, Qb, Kb, Vb);
  attn_kernel<<<dim3(96, 8), 256, 0, stream>>>(Qb, Kb, Vb, out);
}

// Round 5
// 149.509 us; speedup vs baseline: 1.0517x; 1.0130x over previous
//
#include <hip/hip_runtime.h>
#include <stdint.h>

typedef __bf16 bf16;
typedef __attribute__((ext_vector_type(8))) __bf16 bf16x8;
typedef __attribute__((ext_vector_type(4))) __bf16 bf16x4;
typedef __attribute__((ext_vector_type(4))) float  f32x4;

#define ATT_SCALE 0.125f   // 1/sqrt(64), folded into Q at GEMM epilogue

// ---------------------------------------------------------------------------
// async 16B global -> LDS (wave-uniform LDS base + lane*16, per-lane gaddr)
// ---------------------------------------------------------------------------
__device__ __forceinline__ void async16(void* lds, const void* g) {
  __builtin_amdgcn_global_load_lds(
      (__attribute__((address_space(1))) void*)(void*)g,
      (__attribute__((address_space(3))) void*)lds,
      16, 0, 0);
}

// ---------------------------------------------------------------------------
// Fused prep: blocks [0,3072) convert x fp32->bf16 (8 elems/thread);
//             blocks [3072,4800) transpose W [768x2304] fp32 -> Wt bf16.
// ---------------------------------------------------------------------------
__global__ void prep_kernel(const float* __restrict__ x, bf16* __restrict__ y,
                            const float* __restrict__ W, bf16* __restrict__ Wt) {
  __shared__ float tile[32][33];
  const int tid = threadIdx.x;
  if (blockIdx.x < 3072) {
    size_t i = ((size_t)blockIdx.x * 256 + tid) * 8;
    float4 a = *(const float4*)(x + i);
    float4 b = *(const float4*)(x + i + 4);
    bf16x8 o;
    o[0] = (bf16)a.x; o[1] = (bf16)a.y; o[2] = (bf16)a.z; o[3] = (bf16)a.w;
    o[4] = (bf16)b.x; o[5] = (bf16)b.y; o[6] = (bf16)b.z; o[7] = (bf16)b.w;
    *(bf16x8*)(y + i) = o;
  } else {
    const int bid = blockIdx.x - 3072;        // 0..1727
    const int tx = tid & 31, ty = tid >> 5;   // 32 x 8
    const int n0 = (bid % 72) * 32, k0 = (bid / 72) * 32;
#pragma unroll
    for (int r = 0; r < 4; ++r)
      tile[ty + r * 8][tx] = W[(size_t)(k0 + ty + r * 8) * 2304 + n0 + tx];
    __syncthreads();
#pragma unroll
    for (int r = 0; r < 4; ++r)
      Wt[(size_t)(n0 + ty + r * 8) * 768 + k0 + tx] = (bf16)tile[tx][ty + r * 8];
  }
}

// ---------------------------------------------------------------------------
// QKV GEMM (round-0 proven structure) + XCD-aware block swizzle.
//   FETCH_SIZE was 70 MB vs 16 MB ideal: A-panels (196 KB, shared by 18
//   consecutive flat wgids) were replicated across all 8 XCD L2s by the
//   round-robin dispatch. Bijective chunked swizzle (1152 % 8 == 0):
//   XCD k gets swz in [k*144,(k+1)*144) = 8 contiguous m-panels; per-XCD
//   working set A 1.5 MB + B 3.5 MB ~ L2-fit.
// ---------------------------------------------------------------------------
__global__ void qkv_gemm_kernel(const bf16* __restrict__ A, const bf16* __restrict__ Bw,
                                const float* __restrict__ bias,
                                bf16* __restrict__ Qo, bf16* __restrict__ Ko,
                                bf16* __restrict__ Vo) {
  __shared__ __align__(16) char lds[65536];   // 2 x (A 16KB + B 16KB)

  const int tid  = threadIdx.x;
  const int wave = tid >> 6, lane = tid & 63;
  const int quad = lane >> 4, mn = lane & 15;
  const int wr = wave >> 1, wc = wave & 1;

  // XCD swizzle: orig dispatch id -> contiguous per-XCD chunk (144 blocks)
  const int orig = blockIdx.y * 18 + blockIdx.x;   // hw flat id (x fastest)
  const int swz  = (orig & 7) * 144 + (orig >> 3); // 1152 = 8 * 144, bijective
  const int m0 = (swz / 18) * 128;
  const int n0 = (swz % 18) * 128;

  f32x4 acc[4][4] = {};

  const int lrow = lane >> 3;           // 0..7  (row within 8-row group)
  const int cg   = (lane & 7) ^ lrow;   // global 16B-chunk index (swizzled)

  auto stage = [&](int kt, char* buf) {
    char* Al = buf;
    char* Bl = buf + 16384;
#pragma unroll
    for (int u = 0; u < 4; ++u) {
      const int t   = wave * 4 + u;      // 8-row group 0..15
      const int row = t * 8 + lrow;      // tile row 0..127
      async16(Al + t * 1024 + lane * 16,
              A  + (size_t)(m0 + row) * 768 + kt + cg * 8);
      async16(Bl + t * 1024 + lane * 16,
              Bw + (size_t)(n0 + row) * 768 + kt + cg * 8);
    }
  };

  stage(0, lds);
  int p = 0;
  for (int kt = 0; kt < 768; kt += 64) {
    __syncthreads();                     // drains DMA into buf p
    if (kt + 64 < 768) stage(kt + 64, lds + (p ^ 1) * 32768);  // prefetch
    char* Al = lds + p * 32768;
    char* Bl = Al + 16384;

#pragma unroll
    for (int s = 0; s < 2; ++s) {        // two K=32 steps within BK=64
      bf16x8 af[4], bfr[4];
      const int csw = ((s * 4 + quad) ^ (mn & 7)) * 16;  // swizzled chunk offset
#pragma unroll
      for (int i = 0; i < 4; ++i) {
        af[i]  = *(const bf16x8*)(Al + (wr * 64 + i * 16 + mn) * 128 + csw);
        bfr[i] = *(const bf16x8*)(Bl + (wc * 64 + i * 16 + mn) * 128 + csw);
      }
#pragma unroll
      for (int i = 0; i < 4; ++i)
#pragma unroll
        for (int j = 0; j < 4; ++j)
          acc[i][j] = __builtin_amdgcn_mfma_f32_16x16x32_bf16(af[i], bfr[j], acc[i][j], 0, 0, 0);
    }
    p ^= 1;
  }

  // epilogue
  const int ng    = n0 + wc * 64;
  const int third = ng / 768;           // 0=Q 1=K 2=V
  const int nmod  = ng % 768;
  const float sc  = (third == 0) ? ATT_SCALE : 1.0f;
#pragma unroll
  for (int ct = 0; ct < 4; ++ct) {
    int n = nmod + ct * 16 + mn;
    int h = n >> 6, d = n & 63;
    float bv = bias[third * 768 + n];
#pragma unroll
    for (int rt = 0; rt < 4; ++rt) {
      int m  = m0 + wr * 64 + rt * 16 + quad * 4;
      int b  = m >> 10, t0 = m & 1023;
      size_t bh = (size_t)b * 12 + h;
      if (third == 2) {
        bf16x4 pk;
#pragma unroll
        for (int r = 0; r < 4; ++r) pk[r] = (bf16)(acc[rt][ct][r] + bv);
        *(bf16x4*)(Vo + (bh * 64 + d) * 1024 + t0) = pk;   // V^T
      } else {
        bf16* dst = (third == 0 ? Qo : Ko) + (bh * 1024 + t0) * 64 + d;
#pragma unroll
        for (int r = 0; r < 4; ++r) dst[(size_t)r * 64] = (bf16)((acc[rt][ct][r] + bv) * sc);
      }
    }
  }
}

// ---------------------------------------------------------------------------
// Attention v7 = v6's counted-vmcnt prefetch at distance 1 with DOUBLE-
//   buffered KV -> LDS 48KB -> 3 blocks/CU. Grid 768 blocks == 768 resident
//   slots: exactly one dispatch round (v6's 64KB/2-per-CU was 1.5 rounds,
//   75% slot efficiency, and only 2 waves/SIMD for latency hiding).
//   Per-iter two-barrier phase (round-3 fence discipline throughout):
//     lgkm-drain; BAR-A   (closes iter j-1 reads -> WAR gate)
//     stage(j+1) -> buf (j+1)&1   (the buffer read in j-1)
//     vmcnt(4)            (own stage j complete; stage j+1 stays in flight;
//                          j=0: oldest-8 wait also covers the 4 Q-loads)
//     BAR-B               (publishes ALL waves' stage j)
//     compute on buf j&1  (S rows wave-private, no barrier inside)
//   vmcnt(0) only at the last iteration (pipeline provably starved).
// ---------------------------------------------------------------------------
__global__ __launch_bounds__(256, 3)
void attn_kernel(const bf16* __restrict__ Q, const bf16* __restrict__ K,
                 const bf16* __restrict__ Vt, float* __restrict__ out) {
  __shared__ __align__(16) char lds[49152];
  // buf c at lds + c*16384 (c = j&1): K 64x128B then V 64x128B (XOR-swizzled)
  char* ldsS = lds + 32768;              // 128 rows x 128B (A-half, B-half)

  const int tid  = threadIdx.x;
  const int wave = tid >> 6, lane = tid & 63;
  const int quad = lane >> 4, mn = lane & 15;
  const int bh  = blockIdx.x;
  const int qta = blockIdx.y;            // 0..7
  const int qtb = 15 - qta;              // 8..15
  const int qa0 = qta * 64, qb0 = qtb * 64;

  const bf16* Qg  = Q  + (size_t)bh * 65536;
  const bf16* Kg0 = K  + (size_t)bh * 65536;
  const bf16* Vg0 = Vt + (size_t)bh * 65536;

#define SCHED0() __builtin_amdgcn_sched_barrier(0)

  // Q fragments: lane mn -> row base+mn, d = quad*8.. / 32+quad*8..
  bf16x8 qfA[2], qfB[2];
  {
    const bf16* ra = Qg + (size_t)(qa0 + wave * 16 + mn) * 64;
    qfA[0] = *(const bf16x8*)(ra + quad * 8);
    qfA[1] = *(const bf16x8*)(ra + 32 + quad * 8);
    const bf16* rb = Qg + (size_t)(qb0 + wave * 16 + mn) * 64;
    qfB[0] = *(const bf16x8*)(rb + quad * 8);
    qfB[1] = *(const bf16x8*)(rb + 32 + quad * 8);
  }
  SCHED0();   // pin Q-loads before the staged DMA (vmcnt order discipline)

  f32x4 yA[4] = {}, yB[4] = {};

  const int lrow = lane >> 3;            // 0..7
  const int cg   = (lane & 7) ^ lrow;    // swizzled global chunk

  auto stageKV = [&](int j, char* buf) {
#pragma unroll
    for (int u2 = 0; u2 < 2; ++u2) {
      const int u   = wave * 2 + u2;     // 8-row group 0..7
      const int row = u * 8 + lrow;      // 0..63
      async16(buf + u * 1024 + lane * 16,
              Kg0 + (size_t)(j * 64 + row) * 64 + cg * 8);
      async16(buf + 8192 + u * 1024 + lane * 16,
              Vg0 + (size_t)row * 1024 + j * 64 + cg * 8);
    }
  };

  const int srow = (wave * 16 + mn) * 128;   // within a half (half adds 8192)

  // prologue: stage tile 0 only (stage 1 issued inside iter 0 after BAR-A)
  stageKV(0, lds);  SCHED0();

  for (int j = 0; j <= qtb; ++j) {
    // drain own ds ops, then BAR-A: all waves finished iter j-1 LDS reads
    asm volatile("s_waitcnt lgkmcnt(0)" ::: "memory"); SCHED0();
    __builtin_amdgcn_s_barrier(); SCHED0();
    if (j < qtb) { stageKV(j + 1, lds + ((j + 1) & 1) * 16384); SCHED0(); }
    // complete own stage j (leave stage j+1 in flight), then publish
    if (j < qtb) { asm volatile("s_waitcnt vmcnt(4)" ::: "memory"); }
    else         { asm volatile("s_waitcnt vmcnt(0)" ::: "memory"); }
    SCHED0();
    __builtin_amdgcn_s_barrier(); SCHED0();

    char* bK = lds + (j & 1) * 16384;
    char* bV = bK + 8192;

    // hoisted K/V fragments (shared by both halves)
    bf16x8 kf[4][2], vf[4][2];
    const int sw = mn & 7;
#pragma unroll
    for (int ct = 0; ct < 4; ++ct) {
      const int ro = (ct * 16 + mn) * 128;
      kf[ct][0] = *(const bf16x8*)(bK + ro + ((quad)     ^ sw) * 16);
      kf[ct][1] = *(const bf16x8*)(bK + ro + ((4 + quad) ^ sw) * 16);
      vf[ct][0] = *(const bf16x8*)(bV + ro + ((quad)     ^ sw) * 16);
      vf[ct][1] = *(const bf16x8*)(bV + ro + ((4 + quad) ^ sw) * 16);
    }

    auto qk_half = [&](const bf16x8* qf, int half, int qrow, bool diag) {
      // S^T = K Q^T: lane holds (kk = j*64+ct*16+quad*4+r, q = qrow=base+mn)
#pragma unroll
      for (int ct = 0; ct < 4; ++ct) {
        f32x4 a = {};
        a = __builtin_amdgcn_mfma_f32_16x16x32_bf16(kf[ct][0], qf[0], a, 0, 0, 0);
        a = __builtin_amdgcn_mfma_f32_16x16x32_bf16(kf[ct][1], qf[1], a, 0, 0, 0);
        const int kkg = j * 64 + ct * 16 + quad * 4;
        bf16x4 pk;
#pragma unroll
        for (int r = 0; r < 4; ++r) {
          float v = a[r];
          v = v > 0.f ? v : 0.f;
          if (diag && kkg + r > qrow) v = 0.f;
          pk[r] = (bf16)v;
        }
        *(bf16x4*)(ldsS + half * 8192 + srow +
                   (((ct * 4 + quad) ^ (sw << 1)) & 15) * 8) = pk;
      }
    };
    auto sv_half = [&](f32x4* y, int half) {
#pragma unroll
      for (int kb = 0; kb < 2; ++kb) {
        bf16x8 sf = *(const bf16x8*)(ldsS + half * 8192 + srow +
                                     ((kb * 4 + quad) ^ sw) * 16);
#pragma unroll
        for (int ct = 0; ct < 4; ++ct)
          y[ct] = __builtin_amdgcn_mfma_f32_16x16x32_bf16(sf, vf[ct][kb], y[ct], 0, 0, 0);
      }
    };

    if (j <= qta) qk_half(qfA, 0, qa0 + wave * 16 + mn, j == qta);
    qk_half(qfB, 1, qb0 + wave * 16 + mn, j == qtb);
    if (j <= qta) sv_half(yA, 0);
    sv_half(yB, 1);
  }

#undef SCHED0

  // write out: out[b][t][h*64+d]; yacc: q = wave*16+quad*4+r, d = ct*16+mn
  const int b = bh / 12, h = bh % 12;
  {
    float* ob = out + ((size_t)b * 1024 + qa0 + wave * 16 + quad * 4) * 768 + h * 64;
#pragma unroll
    for (int ct = 0; ct < 4; ++ct)
#pragma unroll
      for (int r = 0; r < 4; ++r)
        ob[(size_t)r * 768 + ct * 16 + mn] = yA[ct][r];
  }
  {
    float* ob = out + ((size_t)b * 1024 + qb0 + wave * 16 + quad * 4) * 768 + h * 64;
#pragma unroll
    for (int ct = 0; ct < 4; ++ct)
#pragma unroll
      for (int r = 0; r < 4; ++r)
        ob[(size_t)r * 768 + ct * 16 + mn] = yB[ct][r];
  }
}

// ---------------------------------------------------------------------------
extern "C" void kernel_launch(void* const* d_in, const int* in_sizes, int n_in,
                              void* d_out, int out_size, void* d_ws, size_t ws_size,
                              hipStream_t stream) {
  const float* x    = (const float*)d_in[0];   // [8,1024,768]
  const float* W    = (const float*)d_in[1];   // [768,2304]
  const float* bias = (const float*)d_in[2];   // [2304]
  float* out = (float*)d_out;                  // [8,1024,768]

  char* ws = (char*)d_ws;
  bf16* xb = (bf16*)(ws);                      // 8192*768
  bf16* Wt = (bf16*)(ws + 12582912);           // 2304*768
  bf16* Qb = (bf16*)(ws + 16121856);           // 96*1024*64
  bf16* Kb = (bf16*)(ws + 28704768);           // 96*1024*64
  bf16* Vb = (bf16*)(ws + 41287680);           // 96*64*1024 (V^T)

  prep_kernel<<<4800, 256, 0, stream>>>(x, xb, W, Wt);
  qkv_gemm_kernel<<<dim3(18, 64), 256, 0, stream>>>(xb, Wt, bias, Qb, Kb, Vb);
  attn_kernel<<<dim3(96, 8), 256, 0, stream>>>(Qb, Kb, Vb, out);
}

// Round 6
// 142.379 us; speedup vs baseline: 1.1044x; 1.0501x over previous
//
#include <hip/hip_runtime.h>
#include <stdint.h>

typedef __bf16 bf16;
typedef __attribute__((ext_vector_type(8))) __bf16 bf16x8;
typedef __attribute__((ext_vector_type(4))) __bf16 bf16x4;
typedef __attribute__((ext_vector_type(4))) float  f32x4;

#define ATT_SCALE 0.125f   // 1/sqrt(64), folded into Q at GEMM epilogue

// ---------------------------------------------------------------------------
// async 16B global -> LDS (wave-uniform LDS base + lane*16, per-lane gaddr)
// ---------------------------------------------------------------------------
__device__ __forceinline__ void async16(void* lds, const void* g) {
  __builtin_amdgcn_global_load_lds(
      (__attribute__((address_space(1))) void*)(void*)g,
      (__attribute__((address_space(3))) void*)lds,
      16, 0, 0);
}

// ---------------------------------------------------------------------------
// Fused prep: blocks [0,3072) convert x fp32->bf16 (8 elems/thread);
//             blocks [3072,4800) transpose W [768x2304] fp32 -> Wt bf16.
// ---------------------------------------------------------------------------
__global__ void prep_kernel(const float* __restrict__ x, bf16* __restrict__ y,
                            const float* __restrict__ W, bf16* __restrict__ Wt) {
  __shared__ float tile[32][33];
  const int tid = threadIdx.x;
  if (blockIdx.x < 3072) {
    size_t i = ((size_t)blockIdx.x * 256 + tid) * 8;
    float4 a = *(const float4*)(x + i);
    float4 b = *(const float4*)(x + i + 4);
    bf16x8 o;
    o[0] = (bf16)a.x; o[1] = (bf16)a.y; o[2] = (bf16)a.z; o[3] = (bf16)a.w;
    o[4] = (bf16)b.x; o[5] = (bf16)b.y; o[6] = (bf16)b.z; o[7] = (bf16)b.w;
    *(bf16x8*)(y + i) = o;
  } else {
    const int bid = blockIdx.x - 3072;        // 0..1727
    const int tx = tid & 31, ty = tid >> 5;   // 32 x 8
    const int n0 = (bid % 72) * 32, k0 = (bid / 72) * 32;
#pragma unroll
    for (int r = 0; r < 4; ++r)
      tile[ty + r * 8][tx] = W[(size_t)(k0 + ty + r * 8) * 2304 + n0 + tx];
    __syncthreads();
#pragma unroll
    for (int r = 0; r < 4; ++r)
      Wt[(size_t)(n0 + ty + r * 8) * 768 + k0 + tx] = (bf16)tile[tx][ty + r * 8];
  }
}

// ---------------------------------------------------------------------------
// QKV GEMM v3 = round-0 structure + XCD swizzle (R5, FETCH 70->48 MB) +
//   counted-vmcnt two-barrier K-loop (pattern proven in attn-v7, R5 pass).
//   Old loop: __syncthreads() implies vmcnt(0) -> drains the prefetch it
//   just issued every iteration (~700-900 cyc latency vs ~1 iter of cover,
//   only 2 blocks/CU to overlap) -> MfmaUtil 24%, 4x pipe floor.
//   New per-iter phase (round-3 fence discipline):
//     lgkm-drain; BAR-A            (closes iter j-1 LDS reads -> WAR gate)
//     stage(j+1) -> buf (j+1)&1    (8 loads/wave)
//     vmcnt(8)                     (stage j complete; j+1 stays IN FLIGHT
//                                   across the barrier -> full-iter cover)
//     BAR-B                        (publishes all waves' stage j)
//     compute on buf j&1
//   vmcnt(0) only at the last iteration (pipeline provably starved).
// ---------------------------------------------------------------------------
__global__ void qkv_gemm_kernel(const bf16* __restrict__ A, const bf16* __restrict__ Bw,
                                const float* __restrict__ bias,
                                bf16* __restrict__ Qo, bf16* __restrict__ Ko,
                                bf16* __restrict__ Vo) {
  __shared__ __align__(16) char lds[65536];   // 2 x (A 16KB + B 16KB)

  const int tid  = threadIdx.x;
  const int wave = tid >> 6, lane = tid & 63;
  const int quad = lane >> 4, mn = lane & 15;
  const int wr = wave >> 1, wc = wave & 1;

  // XCD swizzle: orig dispatch id -> contiguous per-XCD chunk (144 blocks)
  const int orig = blockIdx.y * 18 + blockIdx.x;   // hw flat id (x fastest)
  const int swz  = (orig & 7) * 144 + (orig >> 3); // 1152 = 8 * 144, bijective
  const int m0 = (swz / 18) * 128;
  const int n0 = (swz % 18) * 128;

  f32x4 acc[4][4] = {};

  const int lrow = lane >> 3;           // 0..7  (row within 8-row group)
  const int cg   = (lane & 7) ^ lrow;   // global 16B-chunk index (swizzled)

  auto stage = [&](int kt, char* buf) {
    char* Al = buf;
    char* Bl = buf + 16384;
#pragma unroll
    for (int u = 0; u < 4; ++u) {
      const int t   = wave * 4 + u;      // 8-row group 0..15
      const int row = t * 8 + lrow;      // tile row 0..127
      async16(Al + t * 1024 + lane * 16,
              A  + (size_t)(m0 + row) * 768 + kt + cg * 8);
      async16(Bl + t * 1024 + lane * 16,
              Bw + (size_t)(n0 + row) * 768 + kt + cg * 8);
    }
  };

#define SCHED0() __builtin_amdgcn_sched_barrier(0)

  stage(0, lds); SCHED0();

  for (int j = 0; j < 12; ++j) {
    // BAR-A: all waves finished iter j-1 LDS reads (WAR gate for buf (j+1)&1)
    asm volatile("s_waitcnt lgkmcnt(0)" ::: "memory"); SCHED0();
    __builtin_amdgcn_s_barrier(); SCHED0();
    if (j < 11) { stage((j + 1) * 64, lds + ((j + 1) & 1) * 32768); SCHED0(); }
    // complete own stage j (8 loads); leave stage j+1 in flight
    if (j < 11) { asm volatile("s_waitcnt vmcnt(8)" ::: "memory"); }
    else        { asm volatile("s_waitcnt vmcnt(0)" ::: "memory"); }
    SCHED0();
    __builtin_amdgcn_s_barrier(); SCHED0();   // BAR-B: publish stage j

    char* Al = lds + (j & 1) * 32768;
    char* Bl = Al + 16384;

#pragma unroll
    for (int s = 0; s < 2; ++s) {        // two K=32 steps within BK=64
      bf16x8 af[4], bfr[4];
      const int csw = ((s * 4 + quad) ^ (mn & 7)) * 16;  // swizzled chunk offset
#pragma unroll
      for (int i = 0; i < 4; ++i) {
        af[i]  = *(const bf16x8*)(Al + (wr * 64 + i * 16 + mn) * 128 + csw);
        bfr[i] = *(const bf16x8*)(Bl + (wc * 64 + i * 16 + mn) * 128 + csw);
      }
#pragma unroll
      for (int i = 0; i < 4; ++i)
#pragma unroll
        for (int jj = 0; jj < 4; ++jj)
          acc[i][jj] = __builtin_amdgcn_mfma_f32_16x16x32_bf16(af[i], bfr[jj], acc[i][jj], 0, 0, 0);
    }
  }

#undef SCHED0

  // epilogue
  const int ng    = n0 + wc * 64;
  const int third = ng / 768;           // 0=Q 1=K 2=V
  const int nmod  = ng % 768;
  const float sc  = (third == 0) ? ATT_SCALE : 1.0f;
#pragma unroll
  for (int ct = 0; ct < 4; ++ct) {
    int n = nmod + ct * 16 + mn;
    int h = n >> 6, d = n & 63;
    float bv = bias[third * 768 + n];
#pragma unroll
    for (int rt = 0; rt < 4; ++rt) {
      int m  = m0 + wr * 64 + rt * 16 + quad * 4;
      int b  = m >> 10, t0 = m & 1023;
      size_t bh = (size_t)b * 12 + h;
      if (third == 2) {
        bf16x4 pk;
#pragma unroll
        for (int r = 0; r < 4; ++r) pk[r] = (bf16)(acc[rt][ct][r] + bv);
        *(bf16x4*)(Vo + (bh * 64 + d) * 1024 + t0) = pk;   // V^T
      } else {
        bf16* dst = (third == 0 ? Qo : Ko) + (bh * 1024 + t0) * 64 + d;
#pragma unroll
        for (int r = 0; r < 4; ++r) dst[(size_t)r * 64] = (bf16)((acc[rt][ct][r] + bv) * sc);
      }
    }
  }
}

// ---------------------------------------------------------------------------
// Attention v7 (unchanged from R5, passing): counted-vmcnt prefetch at
//   distance 1, double-buffered KV, LDS 48KB -> 3 blocks/CU, 768 blocks =
//   exactly one residency round. Two-barrier phase per iter; vmcnt(0) only
//   at the final starved iteration. S rows wave-private (no barrier between
//   QK and SV).
// ---------------------------------------------------------------------------
__global__ __launch_bounds__(256, 3)
void attn_kernel(const bf16* __restrict__ Q, const bf16* __restrict__ K,
                 const bf16* __restrict__ Vt, float* __restrict__ out) {
  __shared__ __align__(16) char lds[49152];
  // buf c at lds + c*16384 (c = j&1): K 64x128B then V 64x128B (XOR-swizzled)
  char* ldsS = lds + 32768;              // 128 rows x 128B (A-half, B-half)

  const int tid  = threadIdx.x;
  const int wave = tid >> 6, lane = tid & 63;
  const int quad = lane >> 4, mn = lane & 15;
  const int bh  = blockIdx.x;
  const int qta = blockIdx.y;            // 0..7
  const int qtb = 15 - qta;              // 8..15
  const int qa0 = qta * 64, qb0 = qtb * 64;

  const bf16* Qg  = Q  + (size_t)bh * 65536;
  const bf16* Kg0 = K  + (size_t)bh * 65536;
  const bf16* Vg0 = Vt + (size_t)bh * 65536;

#define SCHED0() __builtin_amdgcn_sched_barrier(0)

  // Q fragments: lane mn -> row base+mn, d = quad*8.. / 32+quad*8..
  bf16x8 qfA[2], qfB[2];
  {
    const bf16* ra = Qg + (size_t)(qa0 + wave * 16 + mn) * 64;
    qfA[0] = *(const bf16x8*)(ra + quad * 8);
    qfA[1] = *(const bf16x8*)(ra + 32 + quad * 8);
    const bf16* rb = Qg + (size_t)(qb0 + wave * 16 + mn) * 64;
    qfB[0] = *(const bf16x8*)(rb + quad * 8);
    qfB[1] = *(const bf16x8*)(rb + 32 + quad * 8);
  }
  SCHED0();   // pin Q-loads before the staged DMA (vmcnt order discipline)

  f32x4 yA[4] = {}, yB[4] = {};

  const int lrow = lane >> 3;            // 0..7
  const int cg   = (lane & 7) ^ lrow;    // swizzled global chunk

  auto stageKV = [&](int j, char* buf) {
#pragma unroll
    for (int u2 = 0; u2 < 2; ++u2) {
      const int u   = wave * 2 + u2;     // 8-row group 0..7
      const int row = u * 8 + lrow;      // 0..63
      async16(buf + u * 1024 + lane * 16,
              Kg0 + (size_t)(j * 64 + row) * 64 + cg * 8);
      async16(buf + 8192 + u * 1024 + lane * 16,
              Vg0 + (size_t)row * 1024 + j * 64 + cg * 8);
    }
  };

  const int srow = (wave * 16 + mn) * 128;   // within a half (half adds 8192)

  // prologue: stage tile 0 only (stage 1 issued inside iter 0 after BAR-A)
  stageKV(0, lds);  SCHED0();

  for (int j = 0; j <= qtb; ++j) {
    // drain own ds ops, then BAR-A: all waves finished iter j-1 LDS reads
    asm volatile("s_waitcnt lgkmcnt(0)" ::: "memory"); SCHED0();
    __builtin_amdgcn_s_barrier(); SCHED0();
    if (j < qtb) { stageKV(j + 1, lds + ((j + 1) & 1) * 16384); SCHED0(); }
    // complete own stage j (leave stage j+1 in flight), then publish
    if (j < qtb) { asm volatile("s_waitcnt vmcnt(4)" ::: "memory"); }
    else         { asm volatile("s_waitcnt vmcnt(0)" ::: "memory"); }
    SCHED0();
    __builtin_amdgcn_s_barrier(); SCHED0();

    char* bK = lds + (j & 1) * 16384;
    char* bV = bK + 8192;

    // hoisted K/V fragments (shared by both halves)
    bf16x8 kf[4][2], vf[4][2];
    const int sw = mn & 7;
#pragma unroll
    for (int ct = 0; ct < 4; ++ct) {
      const int ro = (ct * 16 + mn) * 128;
      kf[ct][0] = *(const bf16x8*)(bK + ro + ((quad)     ^ sw) * 16);
      kf[ct][1] = *(const bf16x8*)(bK + ro + ((4 + quad) ^ sw) * 16);
      vf[ct][0] = *(const bf16x8*)(bV + ro + ((quad)     ^ sw) * 16);
      vf[ct][1] = *(const bf16x8*)(bV + ro + ((4 + quad) ^ sw) * 16);
    }

    auto qk_half = [&](const bf16x8* qf, int half, int qrow, bool diag) {
      // S^T = K Q^T: lane holds (kk = j*64+ct*16+quad*4+r, q = qrow=base+mn)
#pragma unroll
      for (int ct = 0; ct < 4; ++ct) {
        f32x4 a = {};
        a = __builtin_amdgcn_mfma_f32_16x16x32_bf16(kf[ct][0], qf[0], a, 0, 0, 0);
        a = __builtin_amdgcn_mfma_f32_16x16x32_bf16(kf[ct][1], qf[1], a, 0, 0, 0);
        const int kkg = j * 64 + ct * 16 + quad * 4;
        bf16x4 pk;
#pragma unroll
        for (int r = 0; r < 4; ++r) {
          float v = a[r];
          v = v > 0.f ? v : 0.f;
          if (diag && kkg + r > qrow) v = 0.f;
          pk[r] = (bf16)v;
        }
        *(bf16x4*)(ldsS + half * 8192 + srow +
                   (((ct * 4 + quad) ^ (sw << 1)) & 15) * 8) = pk;
      }
    };
    auto sv_half = [&](f32x4* y, int half) {
#pragma unroll
      for (int kb = 0; kb < 2; ++kb) {
        bf16x8 sf = *(const bf16x8*)(ldsS + half * 8192 + srow +
                                     ((kb * 4 + quad) ^ sw) * 16);
#pragma unroll
        for (int ct = 0; ct < 4; ++ct)
          y[ct] = __builtin_amdgcn_mfma_f32_16x16x32_bf16(sf, vf[ct][kb], y[ct], 0, 0, 0);
      }
    };

    if (j <= qta) qk_half(qfA, 0, qa0 + wave * 16 + mn, j == qta);
    qk_half(qfB, 1, qb0 + wave * 16 + mn, j == qtb);
    if (j <= qta) sv_half(yA, 0);
    sv_half(yB, 1);
  }

#undef SCHED0

  // write out: out[b][t][h*64+d]; yacc: q = wave*16+quad*4+r, d = ct*16+mn
  const int b = bh / 12, h = bh % 12;
  {
    float* ob = out + ((size_t)b * 1024 + qa0 + wave * 16 + quad * 4) * 768 + h * 64;
#pragma unroll
    for (int ct = 0; ct < 4; ++ct)
#pragma unroll
      for (int r = 0; r < 4; ++r)
        ob[(size_t)r * 768 + ct * 16 + mn] = yA[ct][r];
  }
  {
    float* ob = out + ((size_t)b * 1024 + qb0 + wave * 16 + quad * 4) * 768 + h * 64;
#pragma unroll
    for (int ct = 0; ct < 4; ++ct)
#pragma unroll
      for (int r = 0; r < 4; ++r)
        ob[(size_t)r * 768 + ct * 16 + mn] = yB[ct][r];
  }
}

// ---------------------------------------------------------------------------
extern "C" void kernel_launch(void* const* d_in, const int* in_sizes, int n_in,
                              void* d_out, int out_size, void* d_ws, size_t ws_size,
                              hipStream_t stream) {
  const float* x    = (const float*)d_in[0];   // [8,1024,768]
  const float* W    = (const float*)d_in[1];   // [768,2304]
  const float* bias = (const float*)d_in[2];   // [2304]
  float* out = (float*)d_out;                  // [8,1024,768]

  char* ws = (char*)d_ws;
  bf16* xb = (bf16*)(ws);                      // 8192*768
  bf16* Wt = (bf16*)(ws + 12582912);           // 2304*768
  bf16* Qb = (bf16*)(ws + 16121856);           // 96*1024*64
  bf16* Kb = (bf16*)(ws + 28704768);           // 96*1024*64
  bf16* Vb = (bf16*)(ws + 41287680);           // 96*64*1024 (V^T)

  prep_kernel<<<4800, 256, 0, stream>>>(x, xb, W, Wt);
  qkv_gemm_kernel<<<dim3(18, 64), 256, 0, stream>>>(xb, Wt, bias, Qb, Kb, Vb);
  attn_kernel<<<dim3(96, 8), 256, 0, stream>>>(Qb, Kb, Vb, out);
}